// Round 13
// baseline (244.139 us; speedup 1.0000x reference)
//
#include <hip/hip_runtime.h>
#include <hip/hip_bf16.h>

// LSTM_Actor v11b: v11 with the stepB missing-h bug fixed via parity-dependent
// h row storage. 256 blocks x 512 threads (8 waves), 8 rows/block.
// A (M=16) x-pair packing: A-row 2q = x(t) row q, 2q+1 = x(t+1) row q.
// h storage: par0 buffer (read by stepA) holds h at EVEN A-rows; par1 buffer
// (read by stepB) holds h at ODD A-rows. Thus stepA gates read C rows m0/m2
// and stepB gates read m1/m3 -- in both cases the SAME rows carry the x-pair
// contribution, so h-MFMA chains directly onto the carried x-acc (no adds).
// Weights pre-scaled by -log2e (i,f,o) / +2log2e (g): activation =
// rcp(1+exp2(y)). One lgkm-only barrier per step; single x LDS buffer
// (write stepA, read stepB); DPP row_ror:8 exchange; 8-step unroll.

#define TT 512
#define BB 2048
#define DD 64
#define AA 16
#define ROWB 384   // bytes/A-row: x 128B | h par0 128B | h par1 128B

typedef short bf16x8 __attribute__((ext_vector_type(8)));
typedef float f32x4 __attribute__((ext_vector_type(4)));

#define MFMA16(a, b, c) __builtin_amdgcn_mfma_f32_16x16x32_bf16((a), (b), (c), 0, 0, 0)

#if defined(__has_builtin)
#  if __has_builtin(__builtin_amdgcn_exp2f)
#    define EXP2F(x) __builtin_amdgcn_exp2f(x)
#  else
#    define EXP2F(x) exp2f(x)
#  endif
#  if __has_builtin(__builtin_amdgcn_rcpf)
#    define RCPF(x) __builtin_amdgcn_rcpf(x)
#  else
#    define RCPF(x) (1.0f/(x))
#  endif
#else
#  define EXP2F(x) exp2f(x)
#  define RCPF(x) (1.0f/(x))
#endif

#define GS_I (-1.4426950408889634f)   // sigmoid gates pre-scale
#define GS_G (2.8853900817779268f)    // tanh gate pre-scale

__device__ __forceinline__ unsigned short bfu(float f) {  // RNE fp32->bf16 bits
  union { __hip_bfloat16 b; unsigned short u; } cv;
  cv.b = __float2bfloat16(f);
  return cv.u;
}
__device__ __forceinline__ unsigned cvtpk2(float a, float b) {  // [b|a] bf16 RNE
  union { __hip_bfloat162 b2; unsigned u; } cv;
  cv.b2 = __float22bfloat162_rn(make_float2(a, b));
  return cv.u;
}
// xor-by-8 across lanes via DPP row_ror:8 (HW-validated in v9/v10).
__device__ __forceinline__ float dpp_xor8(float v) {
  int i = __builtin_bit_cast(int, v);
  int r = __builtin_amdgcn_update_dpp(i, i, 0x128, 0xF, 0xF, true);
  return __builtin_bit_cast(float, r);
}
// 16B-slot swizzle within a 128B region; (row&8)>>3 makes same-parity rows
// land on 8 distinct slots.
__device__ __forceinline__ int swz(int row, int slot) {
  return (slot ^ (row & 7) ^ ((row & 8) >> 3)) & 7;
}
// lgkm-only barrier: LDS writes visible; global loads stay in flight.
__device__ __forceinline__ void block_sync_lds() {
  __builtin_amdgcn_sched_barrier(0);
  asm volatile("s_waitcnt lgkmcnt(0)" ::: "memory");
  __builtin_amdgcn_s_barrier();
  __builtin_amdgcn_sched_barrier(0);
}

__global__ __launch_bounds__(512, 2)
void lstm_actor_v11b(const float* __restrict__ x,
                     const float* __restrict__ W_ih,
                     const float* __restrict__ W_hh,
                     const float* __restrict__ b_ih,
                     const float* __restrict__ b_hh,
                     const float* __restrict__ W_out,
                     const float* __restrict__ b_out,
                     float* __restrict__ out) {
  __shared__ __align__(16) unsigned short act[16 * ROWB / 2];  // 6 KB
  char* actb = (char*)act;

  const int tid  = threadIdx.x;
  const int lane = tid & 63;
  const int w    = tid >> 6;       // wave 0..7: j-slice j0 = 8w
  const int lr   = lane & 15;
  const int lg   = lane >> 4;
  const int qq   = lr >> 3;        // 0/1: quadrant within tile pair
  const int jj   = lr & 7;
  const int r0   = blockIdx.x * 8;
  const int j0   = w * 8;

  const f32x4 Z = {0.f, 0.f, 0.f, 0.f};

  // ---- weights (bf16, PRE-SCALED): 2 packed N-tiles x 2 k-frags each ----
  // gate = nt*2+qq: 0=i,1=f,2=g,3=o. Scale GS_G for g, GS_I otherwise.
  bf16x8 Bih[2][2], Bhh[2][2];
  float biasv[2];
#pragma unroll
  for (int nt = 0; nt < 2; ++nt) {
    const int g = (nt * 2 + qq) * 64 + j0 + jj;
    const float sc = (nt == 1 && qq == 0) ? GS_G : GS_I;
    biasv[nt] = sc * (b_ih[g] + b_hh[g]);
#pragma unroll
    for (int kt = 0; kt < 2; ++kt) {
      const float* si = W_ih + g * 64 + kt * 32 + lg * 8;
      const float* sh = W_hh + g * 64 + kt * 32 + lg * 8;
      bf16x8 vi, vh;
#pragma unroll
      for (int u = 0; u < 8; ++u) {
        vi[u] = (short)bfu(sc * si[u]);
        vh[u] = (short)bfu(sc * sh[u]);
      }
      Bih[nt][kt] = vi; Bhh[nt][kt] = vh;
    }
  }

  // ---- projection weights (unscaled, all waves) ----
  bf16x8 pb[2];
  const float bo = b_out[lr];
#pragma unroll
  for (int kt = 0; kt < 2; ++kt) {
    const float* src = W_out + lr * 64 + kt * 32 + lg * 8;
    bf16x8 vh;
#pragma unroll
    for (int u = 0; u < 8; ++u) vh[u] = (short)bfu(src[u]);
    pb[kt] = vh;
  }

  // ---- LDS geometry: x @0, h par0 @128, h par1 @256 (per A-row) ----
  int aoffX[2], aoffH0[2], aoffH1[2];
#pragma unroll
  for (int kt = 0; kt < 2; ++kt) {
    aoffX[kt]  = lr * ROWB + swz(lr, kt * 4 + lg) * 16;
    aoffH0[kt] = aoffX[kt] + 128;
    aoffH1[kt] = aoffX[kt] + 256;
  }
  const int hrow = 2 * lg + qq;
  // par0 (read by stepA): h at EVEN A-row 2*hrow
  const int hW0 = (2 * hrow) * ROWB + 128 + swz(2 * hrow, w) * 16 + 2 * jj;
  // par1 (read by stepB): h at ODD A-row 2*hrow+1
  const int hW1 = (2 * hrow + 1) * ROWB + 256 + swz(2 * hrow + 1, w) * 16 + 2 * jj;
  const int xrow = 2 * w + (lane >> 5);
  const int xj   = 2 * (lane & 31);
  const int xWb  = xrow * ROWB + swz(xrow, xj >> 3) * 16 + ((2 * xj) & 15);

  // ---- zero LDS (h(-1)=0; unused-parity rows stay zero forever) ----
  for (int i = tid; i < 16 * ROWB / 4; i += 512) ((unsigned*)act)[i] = 0u;
  __syncthreads();

  // ---- stage x(0)/x(1); prefetch x(2,3), x(4,5) ----
  const float* xgl = x + (size_t)(r0 + w) * DD + xj + (size_t)(lane >> 5) * BB * DD;
  {
    const float2 v = *(const float2*)xgl;
    *(unsigned*)(actb + xWb) = cvtpk2(v.x, v.y);
  }
  float2 xw = *(const float2*)(xgl + (size_t)2 * BB * DD);
  float2 xf = *(const float2*)(xgl + (size_t)4 * BB * DD);
  xgl += (size_t)6 * BB * DD;
  __syncthreads();

  // ---- prologue x-pass: xC(0) ----
  f32x4 xPa = {biasv[0], biasv[0], biasv[0], biasv[0]};
  f32x4 xPb = {biasv[1], biasv[1], biasv[1], biasv[1]};
  {
    const bf16x8 X0 = *(const bf16x8*)(actb + aoffX[0]);
    const bf16x8 X1 = *(const bf16x8*)(actb + aoffX[1]);
    xPa = MFMA16(X0, Bih[0][0], xPa); xPa = MFMA16(X1, Bih[0][1], xPa);
    xPb = MFMA16(X0, Bih[1][0], xPb); xPb = MFMA16(X1, Bih[1][1], xPb);
  }
  f32x4 xQa = Z, xQb = Z;
  float c_state = 0.0f;
  block_sync_lds();   // prologue x reads complete before stepA(0) overwrites

  // ---- per-step pieces ----
  auto gates_and_h = [&](float a0, float b0, float a1, float b1, int hWoff) {
    // a0/b0 = tile0 rows 2lg/2lg+1; a1/b1 = tile1. All pre-scaled.
    const float rcv0 = dpp_xor8(qq ? a0 : b0);
    const float rcv1 = dpp_xor8(qq ? a1 : b1);
    const float iv_ = qq ? rcv0 : a0;
    const float fv_ = qq ? b0 : rcv0;
    const float gv_ = qq ? rcv1 : a1;
    const float ov_ = qq ? b1 : rcv1;
    const float iv = RCPF(1.0f + EXP2F(iv_));
    const float fv = RCPF(1.0f + EXP2F(fv_));
    const float gv = fmaf(-2.0f, RCPF(1.0f + EXP2F(gv_)), 1.0f);
    const float ov = RCPF(1.0f + EXP2F(ov_));
    c_state = fmaf(fv, c_state, iv * gv);
    const float tc = fmaf(-2.0f, RCPF(1.0f + EXP2F(GS_G * c_state)), 1.0f);
    *(unsigned short*)(actb + hWoff) = bfu(ov * tc);
  };
  // sel: which C-row parity holds real data (0 = even rows m0/m2, 1 = odd).
  auto proj = [&](int t, int tmod, int sel, const bf16x8& A2, const bf16x8& A3) {
    if (w == tmod && t > 0) {
      f32x4 pacc = MFMA16(A2, pb[0], Z);
      pacc = MFMA16(A3, pb[1], pacc);
      const size_t base = ((size_t)(t - 1) * BB + r0 + 2 * lg) * AA + lr;
      out[base]      = pacc[sel]     + bo;
      out[base + AA] = pacc[sel + 2] + bo;
    }
  };
  auto stepA = [&](int t, int tmod, const f32x4& ca, const f32x4& cb) {
    const bf16x8 A2 = *(const bf16x8*)(actb + aoffH0[0]);  // par0: h even rows
    const bf16x8 A3 = *(const bf16x8*)(actb + aoffH0[1]);
    f32x4 H0 = MFMA16(A2, Bhh[0][0], ca); H0 = MFMA16(A3, Bhh[0][1], H0);
    f32x4 H1 = MFMA16(A2, Bhh[1][0], cb); H1 = MFMA16(A3, Bhh[1][1], H1);
    proj(t, tmod, 0, A2, A3);
    // stage x-pair for iter (t/2)+1; rotate prefetch; issue next loads
    *(unsigned*)(actb + xWb) = cvtpk2(xw.x, xw.y);
    xw = xf;
    if (t + 7 < TT) xf = *(const float2*)xgl;
    xgl += (size_t)2 * BB * DD;
    gates_and_h(H0[0], H0[2], H1[0], H1[2], hW1);          // h(t) -> par1 (odd)
    block_sync_lds();
  };
  auto stepB = [&](int t, int tmod, const f32x4& ca, const f32x4& cb,
                   f32x4& na, f32x4& nb) {
    const bf16x8 A2 = *(const bf16x8*)(actb + aoffH1[0]);  // par1: h odd rows
    const bf16x8 A3 = *(const bf16x8*)(actb + aoffH1[1]);
    const bf16x8 X0 = *(const bf16x8*)(actb + aoffX[0]);   // x for it+1
    const bf16x8 X1 = *(const bf16x8*)(actb + aoffX[1]);
    f32x4 H0 = MFMA16(A2, Bhh[0][0], ca); H0 = MFMA16(A3, Bhh[0][1], H0);
    f32x4 H1 = MFMA16(A2, Bhh[1][0], cb); H1 = MFMA16(A3, Bhh[1][1], H1);
    na = (f32x4){biasv[0], biasv[0], biasv[0], biasv[0]};
    nb = (f32x4){biasv[1], biasv[1], biasv[1], biasv[1]};
    na = MFMA16(X0, Bih[0][0], na); na = MFMA16(X1, Bih[0][1], na);
    nb = MFMA16(X0, Bih[1][0], nb); nb = MFMA16(X1, Bih[1][1], nb);
    proj(t, tmod, 1, A2, A3);
    gates_and_h(H0[1], H0[3], H1[1], H1[3], hW0);          // h(t) -> par0 (even)
    block_sync_lds();
  };

  for (int u = 0; u < TT / 8; ++u) {
    const int t0 = u * 8;
    stepA(t0 + 0, 0, xPa, xPb);
    stepB(t0 + 1, 1, xPa, xPb, xQa, xQb);
    stepA(t0 + 2, 2, xQa, xQb);
    stepB(t0 + 3, 3, xQa, xQb, xPa, xPb);
    stepA(t0 + 4, 4, xPa, xPb);
    stepB(t0 + 5, 5, xPa, xPb, xQa, xQb);
    stepA(t0 + 6, 6, xQa, xQb);
    stepB(t0 + 7, 7, xQa, xQb, xPa, xPb);
  }

  // ---- epilogue: out[TT-1] from h(TT-1) (stepB wrote par0, even rows) ----
  if (w == (TT & 7)) {
    const bf16x8 A2 = *(const bf16x8*)(actb + aoffH0[0]);
    const bf16x8 A3 = *(const bf16x8*)(actb + aoffH0[1]);
    f32x4 pacc = MFMA16(A2, pb[0], Z);
    pacc = MFMA16(A3, pb[1], pacc);
    const size_t base = ((size_t)(TT - 1) * BB + r0 + 2 * lg) * AA + lr;
    out[base]      = pacc[0] + bo;
    out[base + AA] = pacc[2] + bo;
  }
}

extern "C" void kernel_launch(void* const* d_in, const int* in_sizes, int n_in,
                              void* d_out, int out_size, void* d_ws, size_t ws_size,
                              hipStream_t stream) {
  const float* x     = (const float*)d_in[0];
  const float* W_ih  = (const float*)d_in[1];
  const float* W_hh  = (const float*)d_in[2];
  const float* b_ih  = (const float*)d_in[3];
  const float* b_hh  = (const float*)d_in[4];
  const float* W_out = (const float*)d_in[5];
  const float* b_out = (const float*)d_in[6];
  float* out = (float*)d_out;

  lstm_actor_v11b<<<dim3(BB / 8), dim3(512), 0, stream>>>(
      x, W_ih, W_hh, b_ih, b_hh, W_out, b_out, out);
}

// Round 14
// 240.225 us; speedup vs baseline: 1.0163x; 1.0163x over previous
//
#include <hip/hip_runtime.h>
#include <hip/hip_bf16.h>

// LSTM_Actor v12: 2 independent blocks/CU + x-QUAD M-packing.
// 512 blocks x 256 threads (4 waves), 4 batch rows/block -> 2 blocks/CU
// (8 waves/CU, 2/SIMD, one per block): independent barriers, stalls overlap.
// A (M=16): A-row 4q+s = x(t0+s)[row q] (x region, quad-packed; fully dense
// x-pass 8 MFMA per 4 steps) ; h at A-rows 4q only (h region; rows 4q+1..3
// zero -> only C[0] read; the waste hides under the VALU/latency budget).
// Wave w owns j-slice [16w,16w+16) as 4 packed N-tiles:
//   tp: gates q=(tp&1)*2+qq at j = j0 + (tp>>1)*8 + jj.
// Lane's C[m=s] of the x-pass = xpart(row lg, t0+s): gates = H[0] + xC[s],
// no cross-lane pair sums. Exchange: 2 DPP row_ror:8 swap (i,g)@jhigh <->
// (f,o)@jlow between qq-halves -> 1 activation chain per lane.
// Weights pre-scaled (-log2e sigmoid / +2log2e tanh). One lgkm-only barrier
// per step. x staged per-quad (float4/lane -> 2 cvtpk -> b64 write), loads
// ride across barriers with ~3-step distance.

#define TT 512
#define BB 2048
#define DD 64
#define AA 16
#define RPB 4
#define ROWB 512   // per A-row: x par0 128 | x par1 128 | h par0 128 | h par1 128

typedef short bf16x8 __attribute__((ext_vector_type(8)));
typedef float f32x4 __attribute__((ext_vector_type(4)));

#define MFMA16(a, b, c) __builtin_amdgcn_mfma_f32_16x16x32_bf16((a), (b), (c), 0, 0, 0)

#if defined(__has_builtin)
#  if __has_builtin(__builtin_amdgcn_exp2f)
#    define EXP2F(x) __builtin_amdgcn_exp2f(x)
#  else
#    define EXP2F(x) exp2f(x)
#  endif
#  if __has_builtin(__builtin_amdgcn_rcpf)
#    define RCPF(x) __builtin_amdgcn_rcpf(x)
#  else
#    define RCPF(x) (1.0f/(x))
#  endif
#else
#  define EXP2F(x) exp2f(x)
#  define RCPF(x) (1.0f/(x))
#endif

#define GS_I (-1.4426950408889634f)   // sigmoid pre-scale
#define GS_G (2.8853900817779268f)    // tanh pre-scale

__device__ __forceinline__ unsigned short bfu(float f) {
  union { __hip_bfloat16 b; unsigned short u; } cv;
  cv.b = __float2bfloat16(f);
  return cv.u;
}
__device__ __forceinline__ unsigned cvtpk2(float a, float b) {  // [b|a] bf16 RNE
  union { __hip_bfloat162 b2; unsigned u; } cv;
  cv.b2 = __float22bfloat162_rn(make_float2(a, b));
  return cv.u;
}
// xor-by-8 across lanes via DPP row_ror:8 (HW-validated v9-v11).
__device__ __forceinline__ float dpp_xor8(float v) {
  int i = __builtin_bit_cast(int, v);
  int r = __builtin_amdgcn_update_dpp(i, i, 0x128, 0xF, 0xF, true);
  return __builtin_bit_cast(float, r);
}
// 16B-slot swizzle within a 128B region.
__device__ __forceinline__ int swz(int row, int slot) {
  return (slot ^ (row & 7) ^ ((row & 8) >> 1)) & 7;
}
// lgkm-only barrier: LDS writes visible; global loads stay in flight.
__device__ __forceinline__ void block_sync_lds() {
  __builtin_amdgcn_sched_barrier(0);
  asm volatile("s_waitcnt lgkmcnt(0)" ::: "memory");
  __builtin_amdgcn_s_barrier();
  __builtin_amdgcn_sched_barrier(0);
}

__global__ __launch_bounds__(256, 2)
void lstm_actor_v12(const float* __restrict__ x,
                    const float* __restrict__ W_ih,
                    const float* __restrict__ W_hh,
                    const float* __restrict__ b_ih,
                    const float* __restrict__ b_hh,
                    const float* __restrict__ W_out,
                    const float* __restrict__ b_out,
                    float* __restrict__ out) {
  __shared__ __align__(16) unsigned short act[16 * ROWB / 2];  // 8 KB
  char* actb = (char*)act;

  const int tid  = threadIdx.x;
  const int lane = tid & 63;
  const int w    = tid >> 6;       // wave 0..3: j0 = 16w; stages x time-slot w
  const int lr   = lane & 15;
  const int lg   = lane >> 4;      // lane's batch row (0..3)
  const int qq   = lr >> 3;
  const int jj   = lr & 7;
  const int r0   = blockIdx.x * RPB;
  const int j0   = w * 16;

  const f32x4 Z = {0.f, 0.f, 0.f, 0.f};

  // ---- weights (bf16, pre-scaled): 4 packed N-tiles x 2 k-frags ----
  bf16x8 Bih[4][2], Bhh[4][2];
  float biasv[4];
#pragma unroll
  for (int tp = 0; tp < 4; ++tp) {
    const int q = (tp & 1) * 2 + qq;            // 0=i,1=f,2=g,3=o
    const int g = q * 64 + j0 + (tp >> 1) * 8 + jj;
    const float sc = (q == 2) ? GS_G : GS_I;
    biasv[tp] = sc * (b_ih[g] + b_hh[g]);
#pragma unroll
    for (int kt = 0; kt < 2; ++kt) {
      const float* si = W_ih + g * 64 + kt * 32 + lg * 8;
      const float* sh = W_hh + g * 64 + kt * 32 + lg * 8;
      bf16x8 vi, vh;
#pragma unroll
      for (int u = 0; u < 8; ++u) {
        vi[u] = (short)bfu(sc * si[u]);
        vh[u] = (short)bfu(sc * sh[u]);
      }
      Bih[tp][kt] = vi; Bhh[tp][kt] = vh;
    }
  }
  bf16x8 pb[2];
  const float bo = b_out[lr];
#pragma unroll
  for (int kt = 0; kt < 2; ++kt) {
    const float* src = W_out + lr * 64 + kt * 32 + lg * 8;
    bf16x8 vh;
#pragma unroll
    for (int u = 0; u < 8; ++u) vh[u] = (short)bfu(src[u]);
    pb[kt] = vh;
  }

  // ---- LDS geometry ----
  const int aoffX0 = lr * ROWB + swz(lr, lg) * 16;          // kt=0
  const int aoffX1 = lr * ROWB + swz(lr, 4 + lg) * 16;      // kt=1
  const int aoffH0 = aoffX0 + 256;
  const int aoffH1 = aoffX1 + 256;
  // h write: lane owns (row lg, j = j0 + qq*8 + jj) -> A-row 4lg
  const int hW = (4 * lg) * ROWB + 256 + swz(4 * lg, 2 * w + qq) * 16 + 2 * jj;
  // x stage: lane covers (row sq, 4 j's at sj*4), wave w = time-slot w
  const int sq  = lane >> 4;
  const int sj  = lane & 15;
  const int xWb = (4 * sq + w) * ROWB + swz(4 * sq + w, sj >> 1) * 16 + (sj & 1) * 8;

  // ---- zero LDS (h(-1)=0; h rows 4q+1..3 stay zero forever) ----
  for (int i = tid; i < 16 * ROWB / 4; i += 256) ((unsigned*)act)[i] = 0u;
  __syncthreads();

  // ---- prologue: stage quad0 (par0) + quad1 (par1); prefetch quad2 ----
  const float* xg0 = x + ((size_t)w * BB + r0 + sq) * DD + sj * 4;
  {
    const float4 v0 = *(const float4*)(xg0);
    const float4 v1 = *(const float4*)(xg0 + (size_t)4 * BB * DD);
    const unsigned long long p0 =
        (unsigned long long)cvtpk2(v0.x, v0.y) | ((unsigned long long)cvtpk2(v0.z, v0.w) << 32);
    const unsigned long long p1 =
        (unsigned long long)cvtpk2(v1.x, v1.y) | ((unsigned long long)cvtpk2(v1.z, v1.w) << 32);
    *(unsigned long long*)(actb + xWb)       = p0;
    *(unsigned long long*)(actb + xWb + 128) = p1;
  }
  float4 xw4 = *(const float4*)(xg0 + (size_t)8 * BB * DD);   // quad2
  const float* xq = xg0 + (size_t)12 * BB * DD;               // next load: quad3
  __syncthreads();

  // ---- prologue x-pass: P = xC(quad0) from parity0 ----
  f32x4 P0 = {biasv[0], biasv[0], biasv[0], biasv[0]};
  f32x4 P1 = {biasv[1], biasv[1], biasv[1], biasv[1]};
  f32x4 P2 = {biasv[2], biasv[2], biasv[2], biasv[2]};
  f32x4 P3 = {biasv[3], biasv[3], biasv[3], biasv[3]};
  {
    const bf16x8 X0 = *(const bf16x8*)(actb + aoffX0);
    const bf16x8 X1 = *(const bf16x8*)(actb + aoffX1);
    P0 = MFMA16(X0, Bih[0][0], P0); P0 = MFMA16(X1, Bih[0][1], P0);
    P1 = MFMA16(X0, Bih[1][0], P1); P1 = MFMA16(X1, Bih[1][1], P1);
    P2 = MFMA16(X0, Bih[2][0], P2); P2 = MFMA16(X1, Bih[2][1], P2);
    P3 = MFMA16(X0, Bih[3][0], P3); P3 = MFMA16(X1, Bih[3][1], P3);
  }
  f32x4 Q0 = Z, Q1 = Z, Q2 = Z, Q3 = Z;
  float c_state = 0.0f;

  // ---- helpers ----
  auto hpass = [&](const bf16x8& A2, const bf16x8& A3,
                   f32x4& H0, f32x4& H1, f32x4& H2, f32x4& H3) {
    H0 = MFMA16(A2, Bhh[0][0], Z);
    H1 = MFMA16(A2, Bhh[1][0], Z);
    H2 = MFMA16(A2, Bhh[2][0], Z);
    H3 = MFMA16(A2, Bhh[3][0], Z);
    H0 = MFMA16(A3, Bhh[0][1], H0);
    H1 = MFMA16(A3, Bhh[1][1], H1);
    H2 = MFMA16(A3, Bhh[2][1], H2);
    H3 = MFMA16(A3, Bhh[3][1], H3);
  };
  auto proj = [&](int t, const bf16x8& A2, const bf16x8& A3) {
    f32x4 pa = MFMA16(A2, pb[0], Z);
    pa = MFMA16(A3, pb[1], pa);
    out[((size_t)(t - 1) * BB + r0 + lg) * AA + lr] = pa[0] + bo;
  };
  auto gates = [&](const f32x4& H0, const f32x4& H1, const f32x4& H2, const f32x4& H3,
                   float c0s, float c1s, float c2s, float c3s, int hwp) {
    const float v0 = H0[0] + c0s;   // tile0: (i or f)@jlow
    const float v1 = H1[0] + c1s;   // tile1: (g or o)@jlow
    const float v2 = H2[0] + c2s;   // tile2: (i or f)@jhigh
    const float v3 = H3[0] + c3s;   // tile3: (g or o)@jhigh
    const float r0v = dpp_xor8(qq ? v0 : v2);
    const float r1v = dpp_xor8(qq ? v1 : v3);
    const float iv_ = qq ? r0v : v0;
    const float fv_ = qq ? v2 : r0v;
    const float gv_ = qq ? r1v : v1;
    const float ov_ = qq ? v3 : r1v;
    const float iv = RCPF(1.0f + EXP2F(iv_));
    const float fv = RCPF(1.0f + EXP2F(fv_));
    const float gv = fmaf(-2.0f, RCPF(1.0f + EXP2F(gv_)), 1.0f);
    const float ov = RCPF(1.0f + EXP2F(ov_));
    c_state = fmaf(fv, c_state, iv * gv);
    const float tc = fmaf(-2.0f, RCPF(1.0f + EXP2F(GS_G * c_state)), 1.0f);
    *(unsigned short*)(actb + hW + hwp) = bfu(ov * tc);
  };

  // ---- one 4-step iteration: consume C*, produce N* (x-quad it+1) ----
  auto iter4 = [&](int t0, const f32x4& C0, const f32x4& C1, const f32x4& C2, const f32x4& C3,
                   f32x4& N0, f32x4& N1, f32x4& N2, f32x4& N3, int xrp, int xsp) {
    // s=0: h par0 -> par1
    {
      const bf16x8 A2 = *(const bf16x8*)(actb + aoffH0);
      const bf16x8 A3 = *(const bf16x8*)(actb + aoffH1);
      f32x4 H0, H1, H2, H3;
      hpass(A2, A3, H0, H1, H2, H3);
      if (w == 0 && t0 > 0) proj(t0, A2, A3);
      gates(H0, H1, H2, H3, C0[0], C1[0], C2[0], C3[0], 128);
      block_sync_lds();
    }
    // s=1: h par1 -> par0; x-read (quad it+1), tiles 0,1
    {
      const bf16x8 A2 = *(const bf16x8*)(actb + aoffH0 + 128);
      const bf16x8 A3 = *(const bf16x8*)(actb + aoffH1 + 128);
      const bf16x8 X0 = *(const bf16x8*)(actb + aoffX0 + xrp);
      const bf16x8 X1 = *(const bf16x8*)(actb + aoffX1 + xrp);
      f32x4 H0, H1, H2, H3;
      hpass(A2, A3, H0, H1, H2, H3);
      N0 = (f32x4){biasv[0], biasv[0], biasv[0], biasv[0]};
      N1 = (f32x4){biasv[1], biasv[1], biasv[1], biasv[1]};
      N0 = MFMA16(X0, Bih[0][0], N0); N0 = MFMA16(X1, Bih[0][1], N0);
      N1 = MFMA16(X0, Bih[1][0], N1); N1 = MFMA16(X1, Bih[1][1], N1);
      if (w == 1) proj(t0 + 1, A2, A3);
      gates(H0, H1, H2, H3, C0[1], C1[1], C2[1], C3[1], 0);
      block_sync_lds();
    }
    // s=2: h par0 -> par1; x tiles 2,3; stage quad(it+2)
    {
      const bf16x8 A2 = *(const bf16x8*)(actb + aoffH0);
      const bf16x8 A3 = *(const bf16x8*)(actb + aoffH1);
      const bf16x8 X0 = *(const bf16x8*)(actb + aoffX0 + xrp);
      const bf16x8 X1 = *(const bf16x8*)(actb + aoffX1 + xrp);
      f32x4 H0, H1, H2, H3;
      hpass(A2, A3, H0, H1, H2, H3);
      N2 = (f32x4){biasv[2], biasv[2], biasv[2], biasv[2]};
      N3 = (f32x4){biasv[3], biasv[3], biasv[3], biasv[3]};
      N2 = MFMA16(X0, Bih[2][0], N2); N2 = MFMA16(X1, Bih[2][1], N2);
      N3 = MFMA16(X0, Bih[3][0], N3); N3 = MFMA16(X1, Bih[3][1], N3);
      const unsigned long long pk =
          (unsigned long long)cvtpk2(xw4.x, xw4.y) |
          ((unsigned long long)cvtpk2(xw4.z, xw4.w) << 32);
      *(unsigned long long*)(actb + xWb + xsp) = pk;
      if (w == 2) proj(t0 + 2, A2, A3);
      gates(H0, H1, H2, H3, C0[2], C1[2], C2[2], C3[2], 128);
      block_sync_lds();
    }
    // s=3: h par1 -> par0; issue loads quad(it+3)
    {
      const bf16x8 A2 = *(const bf16x8*)(actb + aoffH0 + 128);
      const bf16x8 A3 = *(const bf16x8*)(actb + aoffH1 + 128);
      f32x4 H0, H1, H2, H3;
      hpass(A2, A3, H0, H1, H2, H3);
      if (t0 + 12 < TT) xw4 = *(const float4*)xq;
      xq += (size_t)4 * BB * DD;
      if (w == 3) proj(t0 + 3, A2, A3);
      gates(H0, H1, H2, H3, C0[3], C1[3], C2[3], C3[3], 0);
      block_sync_lds();
    }
  };

  for (int u = 0; u < TT / 8; ++u) {
    iter4(8 * u,     P0, P1, P2, P3, Q0, Q1, Q2, Q3, 128, 0);  // it even
    iter4(8 * u + 4, Q0, Q1, Q2, Q3, P0, P1, P2, P3, 0, 128);  // it odd
  }

  // ---- epilogue: out[TT-1] from h(TT-1) (parity 0) ----
  if (w == 0) {
    const bf16x8 A2 = *(const bf16x8*)(actb + aoffH0);
    const bf16x8 A3 = *(const bf16x8*)(actb + aoffH1);
    f32x4 pa = MFMA16(A2, pb[0], Z);
    pa = MFMA16(A3, pb[1], pa);
    out[((size_t)(TT - 1) * BB + r0 + lg) * AA + lr] = pa[0] + bo;
  }
}

extern "C" void kernel_launch(void* const* d_in, const int* in_sizes, int n_in,
                              void* d_out, int out_size, void* d_ws, size_t ws_size,
                              hipStream_t stream) {
  const float* x     = (const float*)d_in[0];
  const float* W_ih  = (const float*)d_in[1];
  const float* W_hh  = (const float*)d_in[2];
  const float* b_ih  = (const float*)d_in[3];
  const float* b_hh  = (const float*)d_in[4];
  const float* W_out = (const float*)d_in[5];
  const float* b_out = (const float*)d_in[6];
  float* out = (float*)d_out;

  lstm_actor_v12<<<dim3(BB / RPB), dim3(256), 0, stream>>>(
      x, W_ih, W_hh, b_ih, b_hh, W_out, b_out, out);
}